// Round 1
// baseline (260.649 us; speedup 1.0000x reference)
//
#include <hip/hip_runtime.h>
#include <hip/hip_bf16.h>
#include <math.h>

#define QLEN 1024
#define MLEN 1024
#define KLEN 2048
#define BSZ 4
#define NH 8
#define DH 64
#define DM 512
#define SCALE 0.125f
#define LN_EPS 1e-5f

#define RK_ROWS 2112   // KLEN + 64 pad rows (pad = harness poison, finite bf16, masked)

typedef __attribute__((ext_vector_type(8))) short short8;   // 8 bf16 (4 VGPRs)
typedef __attribute__((ext_vector_type(4))) float float4_;  // MFMA C/D

#define GLB(p) ((const __attribute__((address_space(1))) void*)(p))
#define LDSP(p) ((__attribute__((address_space(3))) void*)(p))

__device__ inline ushort to_bf16(float x) {
  __hip_bfloat16 h = __float2bfloat16(x);
  return *reinterpret_cast<ushort*>(&h);
}
__device__ inline float bf16_to_f(ushort u) {
  union { unsigned int i; float f; } v;
  v.i = (unsigned int)u << 16;
  return v.f;
}

// 16-lane (row) reductions on the VALU pipe via DPP.
__device__ inline float row_max16(float v) {
  int x = __builtin_bit_cast(int, v);
  v = fmaxf(v, __builtin_bit_cast(float, __builtin_amdgcn_update_dpp(x, x, 0xB1, 0xF, 0xF, false)));
  x = __builtin_bit_cast(int, v);
  v = fmaxf(v, __builtin_bit_cast(float, __builtin_amdgcn_update_dpp(x, x, 0x4E, 0xF, 0xF, false)));
  x = __builtin_bit_cast(int, v);
  v = fmaxf(v, __builtin_bit_cast(float, __builtin_amdgcn_update_dpp(x, x, 0x124, 0xF, 0xF, false)));
  x = __builtin_bit_cast(int, v);
  v = fmaxf(v, __builtin_bit_cast(float, __builtin_amdgcn_update_dpp(x, x, 0x128, 0xF, 0xF, false)));
  return v;
}
__device__ inline float row_sum16(float v) {
  int x = __builtin_bit_cast(int, v);
  v += __builtin_bit_cast(float, __builtin_amdgcn_update_dpp(x, x, 0xB1, 0xF, 0xF, false));
  x = __builtin_bit_cast(int, v);
  v += __builtin_bit_cast(float, __builtin_amdgcn_update_dpp(x, x, 0x4E, 0xF, 0xF, false));
  x = __builtin_bit_cast(int, v);
  v += __builtin_bit_cast(float, __builtin_amdgcn_update_dpp(x, x, 0x124, 0xF, 0xF, false));
  x = __builtin_bit_cast(int, v);
  v += __builtin_bit_cast(float, __builtin_amdgcn_update_dpp(x, x, 0x128, 0xF, 0xF, false));
  return v;
}

// ---------------------------------------------------------------------------
// Fused weight transpose+convert: z selects {Wq, Wkv, Wr, Wo}.
// ---------------------------------------------------------------------------
__global__ __launch_bounds__(256) void wtrans_all(
    const float* __restrict__ Wq, const float* __restrict__ Wkv,
    const float* __restrict__ Wr, const float* __restrict__ Wo,
    ushort* __restrict__ WqT, ushort* __restrict__ WkvT,
    ushort* __restrict__ WrT, ushort* __restrict__ WoT) {
  __shared__ ushort tile[32][33];
  const int z = blockIdx.z;
  const float* W;
  ushort* WT;
  int N;
  if (z == 0)      { W = Wq;  WT = WqT;  N = DM; }
  else if (z == 1) { W = Wkv; WT = WkvT; N = 2 * DM; }
  else if (z == 2) { W = Wr;  WT = WrT;  N = DM; }
  else             { W = Wo;  WT = WoT;  N = DM; }
  const int k0 = blockIdx.x * 32, n0 = blockIdx.y * 32;
  if (n0 >= N) return;
  const int tid = threadIdx.x;
#pragma unroll
  for (int it = 0; it < 4; ++it) {
    int idx = tid + it * 256;
    int r = idx >> 5, c = idx & 31;
    tile[r][c] = to_bf16(W[(size_t)(k0 + r) * N + n0 + c]);
  }
  __syncthreads();
#pragma unroll
  for (int it = 0; it < 4; ++it) {
    int idx = tid + it * 256;
    int r = idx >> 5, c = idx & 31;
    WT[(size_t)(n0 + r) * DM + k0 + c] = tile[c][r];
  }
}

// ---------------------------------------------------------------------------
// Merged MFMA projection GEMM (single dispatch, 704 blocks, 1D decode).
//  mode 0 (128 blk): w @ Wq       -> qw/qr [bn][i][d] (+biases)
//  mode 1 (512 blk): cat @ Wkv    -> k2/v2 packed MFMA-frag order
//  mode 2 ( 64 blk): r @ Wr       -> rk2 LINEAR rows (read from L2 by attn)
// ---------------------------------------------------------------------------
__global__ __launch_bounds__(256) void proj_all(
    const float* __restrict__ w, const float* __restrict__ mems,
    const float* __restrict__ r,
    const ushort* __restrict__ WqT, const ushort* __restrict__ WkvT,
    const ushort* __restrict__ WrT,
    const float* __restrict__ bias0, const float* __restrict__ bias1,
    ushort* __restrict__ qw, ushort* __restrict__ qr,
    ushort* __restrict__ k2, ushort* __restrict__ v2,
    ushort* __restrict__ rk2) {
  __shared__ ushort As[128 * 32];
  __shared__ ushort Bs[128 * 32];
  const int tid = threadIdx.x;
  int mode, bx, by;
  {
    int id = blockIdx.x;
    if (id < 128)      { mode = 0; bx = id >> 2;         by = id & 3; }
    else if (id < 640) { mode = 1; bx = (id - 128) >> 3; by = (id - 128) & 7; }
    else               { mode = 2; bx = (id - 640) >> 2; by = (id - 640) & 3; }
  }
  const int m0 = bx * 128, n0 = by * 128;
  const int wv = tid >> 6, lane = tid & 63;
  const int wm = wv >> 1, wn = wv & 1;
  const int l16 = lane & 15, quad = lane >> 4;

  const int arow = tid >> 1;
  const int acol = (tid & 1) * 16;
  const float* asrc;
  {
    int m = m0 + arow;
    if (mode == 2) asrc = r + (size_t)m * DM;
    else asrc = (m < QLEN * BSZ) ? w + (size_t)m * DM
                                 : mems + (size_t)(m - QLEN * BSZ) * DM;
    asrc += acol;
  }
  const ushort* BT = (mode == 0) ? WqT : (mode == 1) ? WkvT : WrT;
  const ushort* bsrc = BT + (size_t)(n0 + arow) * DM + acol;

  float4_ acc[4][4];
#pragma unroll
  for (int a = 0; a < 4; ++a)
#pragma unroll
    for (int b = 0; b < 4; ++b) acc[a][b] = float4_{0.f, 0.f, 0.f, 0.f};

  for (int k0 = 0; k0 < DM; k0 += 32) {
    // A: 16 f32 -> 16 bf16 convert-in-staging
    float4 a0 = *reinterpret_cast<const float4*>(asrc + k0);
    float4 a1 = *reinterpret_cast<const float4*>(asrc + k0 + 4);
    float4 a2 = *reinterpret_cast<const float4*>(asrc + k0 + 8);
    float4 a3 = *reinterpret_cast<const float4*>(asrc + k0 + 12);
    ushort4 u0, u1, u2, u3;
    u0.x = to_bf16(a0.x); u0.y = to_bf16(a0.y); u0.z = to_bf16(a0.z); u0.w = to_bf16(a0.w);
    u1.x = to_bf16(a1.x); u1.y = to_bf16(a1.y); u1.z = to_bf16(a1.z); u1.w = to_bf16(a1.w);
    u2.x = to_bf16(a2.x); u2.y = to_bf16(a2.y); u2.z = to_bf16(a2.z); u2.w = to_bf16(a2.w);
    u3.x = to_bf16(a3.x); u3.y = to_bf16(a3.y); u3.z = to_bf16(a3.z); u3.w = to_bf16(a3.w);
    *reinterpret_cast<ushort4*>(&As[arow * 32 + acol]) = u0;
    *reinterpret_cast<ushort4*>(&As[arow * 32 + acol + 4]) = u1;
    *reinterpret_cast<ushort4*>(&As[arow * 32 + acol + 8]) = u2;
    *reinterpret_cast<ushort4*>(&As[arow * 32 + acol + 12]) = u3;
    *reinterpret_cast<uint4*>(&Bs[arow * 32 + acol]) =
        *reinterpret_cast<const uint4*>(bsrc + k0);
    *reinterpret_cast<uint4*>(&Bs[arow * 32 + acol + 8]) =
        *reinterpret_cast<const uint4*>(bsrc + k0 + 8);
    __syncthreads();
    short8 af[4], bf[4];
#pragma unroll
    for (int f = 0; f < 4; ++f) {
      af[f] = *reinterpret_cast<const short8*>(&As[(wm * 64 + f * 16 + l16) * 32 + quad * 8]);
      bf[f] = *reinterpret_cast<const short8*>(&Bs[(wn * 64 + f * 16 + l16) * 32 + quad * 8]);
    }
#pragma unroll
    for (int fm = 0; fm < 4; ++fm)
#pragma unroll
      for (int fn = 0; fn < 4; ++fn)  // SWAPPED: reg-dim = n
        acc[fm][fn] = __builtin_amdgcn_mfma_f32_16x16x32_bf16(bf[fn], af[fm], acc[fm][fn], 0, 0, 0);
    __syncthreads();
  }

  // Epilogues: lane (l16,quad) holds C[mm = mtile+l16][nn = ntile+quad*4 + reg]
#pragma unroll
  for (int fm = 0; fm < 4; ++fm) {
#pragma unroll
    for (int fn = 0; fn < 4; ++fn) {
      const int mm = m0 + wm * 64 + fm * 16 + l16;
      const int nnb = n0 + wn * 64 + fn * 16 + quad * 4;
      const float4_ a = acc[fm][fn];
      if (mode == 0) {
        float4 b0v = *reinterpret_cast<const float4*>(bias0 + nnb);
        float4 b1v = *reinterpret_cast<const float4*>(bias1 + nnb);
        int i = mm >> 2, b = mm & 3;
        int hd = nnb >> 6, d0 = nnb & 63;
        size_t idx = (((size_t)(b * NH + hd)) * QLEN + i) * DH + d0;
        ushort4 o0, o1;
        o0.x = to_bf16(a[0] + b0v.x); o0.y = to_bf16(a[1] + b0v.y);
        o0.z = to_bf16(a[2] + b0v.z); o0.w = to_bf16(a[3] + b0v.w);
        o1.x = to_bf16(a[0] + b1v.x); o1.y = to_bf16(a[1] + b1v.y);
        o1.z = to_bf16(a[2] + b1v.z); o1.w = to_bf16(a[3] + b1v.w);
        *reinterpret_cast<ushort4*>(qw + idx) = o0;
        *reinterpret_cast<ushort4*>(qr + idx) = o1;
      } else if (mode == 1) {
        int pos = mm >> 2, b = mm & 3;
        int jb = pos >> 5, jj = pos & 31;
        if (nnb < DM) {
          int hd = nnb >> 6, d = nnb & 63;
          int bn = b * NH + hd;
          int tile = ((jj >> 4) << 1) | (d >> 5);
          int lane2 = (((d >> 3) & 3) << 4) | (jj & 15);
          ushort4 o;
          o.x = to_bf16(a[0]); o.y = to_bf16(a[1]);
          o.z = to_bf16(a[2]); o.w = to_bf16(a[3]);
          *reinterpret_cast<ushort4*>(
              k2 + ((((size_t)bn * 64 + jb) * 4 + tile) * 64 + lane2) * 8 + (d & 7)) = o;
        } else {
          int nn2 = nnb - DM;
          int hd = nn2 >> 6, d = nn2 & 63;
          int bn = b * NH + hd;
          int tile = d >> 4;
          size_t base = ((((size_t)bn * 64 + jb) * 4 + tile) * 64 +
                         ((jj >> 3) << 4)) * 8 + (jj & 7);
#pragma unroll
          for (int reg = 0; reg < 4; ++reg)
            v2[base + (size_t)((d & 15) + reg) * 8] = to_bf16(a[reg]);
        }
      } else {
        int t = mm;  // < 2048
        int hd = nnb >> 6, d = nnb & 63;
        ushort4 o;
        o.x = to_bf16(a[0]); o.y = to_bf16(a[1]);
        o.z = to_bf16(a[2]); o.w = to_bf16(a[3]);
        // LINEAR store (no LDS-bank swizzle needed: attn reads rk2 from L2)
        *reinterpret_cast<ushort4*>(
            rk2 + ((size_t)hd * RK_ROWS + t) * DH + d) = o;
      }
    }
  }
}

// ---------------------------------------------------------------------------
// Output GEMM: y[4096x512] = avbf @ WoT (f32 out).
// ---------------------------------------------------------------------------
__global__ __launch_bounds__(256) void mfma_out(
    const ushort* __restrict__ A, const ushort* __restrict__ BT,
    float* __restrict__ Y) {
  __shared__ ushort As[128 * 32];
  __shared__ ushort Bs[128 * 32];
  const int tid = threadIdx.x;
  const int m0 = blockIdx.x * 128, n0 = blockIdx.y * 128;
  const int wv = tid >> 6, lane = tid & 63;
  const int wm = wv >> 1, wn = wv & 1;
  const int l16 = lane & 15, quad = lane >> 4;
  const int arow = tid >> 1;
  const int acol = (tid & 1) * 16;
  const ushort* asrc = A + (size_t)(m0 + arow) * DM + acol;
  const ushort* bsrc = BT + (size_t)(n0 + arow) * DM + acol;

  float4_ acc[4][4];
#pragma unroll
  for (int a = 0; a < 4; ++a)
#pragma unroll
    for (int b = 0; b < 4; ++b) acc[a][b] = float4_{0.f, 0.f, 0.f, 0.f};

  for (int k0 = 0; k0 < DM; k0 += 32) {
    *reinterpret_cast<uint4*>(&As[arow * 32 + acol]) = *reinterpret_cast<const uint4*>(asrc + k0);
    *reinterpret_cast<uint4*>(&As[arow * 32 + acol + 8]) = *reinterpret_cast<const uint4*>(asrc + k0 + 8);
    *reinterpret_cast<uint4*>(&Bs[arow * 32 + acol]) = *reinterpret_cast<const uint4*>(bsrc + k0);
    *reinterpret_cast<uint4*>(&Bs[arow * 32 + acol + 8]) = *reinterpret_cast<const uint4*>(bsrc + k0 + 8);
    __syncthreads();
    short8 af[4], bf[4];
#pragma unroll
    for (int f = 0; f < 4; ++f) {
      af[f] = *reinterpret_cast<const short8*>(&As[(wm * 64 + f * 16 + l16) * 32 + quad * 8]);
      bf[f] = *reinterpret_cast<const short8*>(&Bs[(wn * 64 + f * 16 + l16) * 32 + quad * 8]);
    }
#pragma unroll
    for (int fm = 0; fm < 4; ++fm)
#pragma unroll
      for (int fn = 0; fn < 4; ++fn)  // SWAPPED
        acc[fm][fn] = __builtin_amdgcn_mfma_f32_16x16x32_bf16(bf[fn], af[fm], acc[fm][fn], 0, 0, 0);
    __syncthreads();
  }
#pragma unroll
  for (int fm = 0; fm < 4; ++fm)
#pragma unroll
    for (int fn = 0; fn < 4; ++fn) {
      int mm = m0 + wm * 64 + fm * 16 + l16;
      int nnb = n0 + wn * 64 + fn * 16 + quad * 4;
      float4 o;
      o.x = acc[fm][fn][0]; o.y = acc[fm][fn][1];
      o.z = acc[fm][fn][2]; o.w = acc[fm][fn][3];
      *reinterpret_cast<float4*>(Y + (size_t)mm * DM + nnb) = o;
    }
}

// ---------------------------------------------------------------------------
// Residual + LayerNorm: one wave per row.
// ---------------------------------------------------------------------------
__global__ __launch_bounds__(256) void ln_fuse(
    const float* __restrict__ y, const float* __restrict__ wres,
    const float* __restrict__ g, const float* __restrict__ bb,
    float* __restrict__ out) {
  const int row = blockIdx.x * 4 + (threadIdx.x >> 6);
  const int lane = threadIdx.x & 63;
  const float* yr = y + (size_t)row * DM + lane * 4;
  const float* wr = wres + (size_t)row * DM + lane * 4;
  float4 x0 = *(const float4*)yr;
  float4 x1 = *(const float4*)(yr + 256);
  float4 w0 = *(const float4*)wr;
  float4 w1 = *(const float4*)(wr + 256);
  x0.x += w0.x; x0.y += w0.y; x0.z += w0.z; x0.w += w0.w;
  x1.x += w1.x; x1.y += w1.y; x1.z += w1.z; x1.w += w1.w;
  float s = x0.x + x0.y + x0.z + x0.w + x1.x + x1.y + x1.z + x1.w;
  float ss = x0.x * x0.x + x0.y * x0.y + x0.z * x0.z + x0.w * x0.w +
             x1.x * x1.x + x1.y * x1.y + x1.z * x1.z + x1.w * x1.w;
#pragma unroll
  for (int off = 1; off <= 32; off <<= 1) {
    s += __shfl_xor(s, off, 64);
    ss += __shfl_xor(ss, off, 64);
  }
  float mu = s * (1.f / DM);
  float var = ss * (1.f / DM) - mu * mu;
  float rstd = rsqrtf(var + LN_EPS);
  float4 g0 = *(const float4*)(g + lane * 4);
  float4 g1 = *(const float4*)(g + lane * 4 + 256);
  float4 b0 = *(const float4*)(bb + lane * 4);
  float4 b1 = *(const float4*)(bb + lane * 4 + 256);
  float4 o0, o1;
  o0.x = (x0.x - mu) * rstd * g0.x + b0.x;
  o0.y = (x0.y - mu) * rstd * g0.y + b0.y;
  o0.z = (x0.z - mu) * rstd * g0.z + b0.z;
  o0.w = (x0.w - mu) * rstd * g0.w + b0.w;
  o1.x = (x1.x - mu) * rstd * g1.x + b1.x;
  o1.y = (x1.y - mu) * rstd * g1.y + b1.y;
  o1.z = (x1.z - mu) * rstd * g1.z + b1.z;
  o1.w = (x1.w - mu) * rstd * g1.w + b1.w;
  float* orow = out + (size_t)row * DM + lane * 4;
  *reinterpret_cast<float4*>(orow) = o0;
  *reinterpret_cast<float4*>(orow + 256) = o1;
}

// ---------------------------------------------------------------------------
// MFMA flash attention, split-K (2 key segments per (i-block, n, b)).
//  - R fragments read directly from global (rk2 = 2.1 MB, L2-resident);
//    LDS staging holds only K|V  -> LDS 37.4 KB -> 4 blocks/CU.
//  - Grid 16 x NH x (BSZ*2) = 1024 blocks -> 4 waves/SIMD (was 2).
//  - Each segment writes unnormalized O (bf16) + (m, l) f32; attn_combine
//    merges the two segments.
// ---------------------------------------------------------------------------
__global__ __launch_bounds__(256, 4) void attn_mfma(
    const ushort* __restrict__ qw, const ushort* __restrict__ qr,
    const ushort* __restrict__ k2, const ushort* __restrict__ v2,
    const ushort* __restrict__ rk2, ushort* __restrict__ Opart,
    float* __restrict__ ml) {
  const int i0b = (gridDim.x - 1 - blockIdx.x) * 64;  // longest blocks first
  const int n = blockIdx.y;
  const int b = blockIdx.z >> 1, seg = blockIdx.z & 1;
  const int bn = b * NH + n;
  const int tid = threadIdx.x;
  const int wv = tid >> 6, lane = tid & 63;
  const int l16 = lane & 15, quad = lane >> 4;
  const int i0w = i0b + wv * 16;

  __shared__ ushort stage[2][8 * 512];   // K 4x512 | V 4x512 (double-buffered)
  __shared__ float Dlds[4][16 * 66];
  __shared__ ushort Plds[4][16 * 32];
  float* __restrict__ Dw = Dlds[wv];
  ushort* __restrict__ Pw = Plds[wv];

  const ushort* __restrict__ k2b = k2 + (size_t)bn * (64 * 4 * 512);
  const ushort* __restrict__ v2b = v2 + (size_t)bn * (64 * 4 * 512);
  const ushort* __restrict__ rk2n = rk2 + (size_t)n * RK_ROWS * DH;

  const int nIterTot = (i0b + 63 + MLEN) / 32 + 1;
  const int nHalf = nIterTot >> 1;
  const int c0 = seg ? nHalf : 0;
  const int c1 = seg ? nIterTot : nHalf;

  short8 aqw0, aqw1, aqr0, aqr1;
  {
    const ushort* qwp = qw + (((size_t)bn * QLEN) + i0w + l16) * DH + quad * 8;
    const ushort* qrp = qr + (((size_t)bn * QLEN) + i0w + l16) * DH + quad * 8;
    aqw0 = *(const short8*)(qwp);
    aqw1 = *(const short8*)(qwp + 32);
    aqr0 = *(const short8*)(qrp);
    aqr1 = *(const short8*)(qrp + 32);
  }

  auto issue_dma = [&](int jb, int buf) {
#pragma unroll
    for (int s = 0; s < 2; ++s) {
      const int m = wv + s * 4;
      const ushort* base = (m < 4) ? k2b : v2b;
      const ushort* g = base + ((size_t)jb * 4 + (m & 3)) * 512 + lane * 8;
      __builtin_amdgcn_global_load_lds(GLB(g), LDSP(&stage[buf][m * 512]), 16, 0, 0);
    }
  };

  float4_ O[4];
#pragma unroll
  for (int t = 0; t < 4; ++t) O[t] = float4_{0.f, 0.f, 0.f, 0.f};
  float mrow[4] = {-INFINITY, -INFINITY, -INFINITY, -INFINITY};
  float lpart[4] = {0.f, 0.f, 0.f, 0.f};
  const float SL2E = SCALE * 1.44269504088896f;
  const int rbase = 48 - 16 * wv;

  issue_dma(c0, 0);
  issue_dma(c0 + 1, 1);

  for (int k = c0; k < c1; ++k) {
    __builtin_amdgcn_s_waitcnt(0x0F72);  // vmcnt<=2
    __builtin_amdgcn_sched_barrier(0);
    __builtin_amdgcn_s_barrier();
    __builtin_amdgcn_sched_barrier(0);
    const ushort* sb = stage[k & 1];
    const int j0 = k * 32;

    // R fragments straight from global (L2-resident, rows linear).
    const int tbase = j0 - i0b + 960;
    short8 rb0[3], rb1[3];
#pragma unroll
    for (int tt = 0; tt < 3; ++tt) {
      const ushort* rrow = rk2n + (size_t)(tbase + rbase + tt * 16 + l16) * DH;
      rb0[tt] = *(const short8*)(rrow + quad * 8);
      rb1[tt] = *(const short8*)(rrow + (4 + quad) * 8);
    }

    float4_ ac[2];
#pragma unroll
    for (int h = 0; h < 2; ++h) {
      short8 b0 = *(const short8*)(sb + (h * 2 + 0) * 512 + lane * 8);
      short8 b1 = *(const short8*)(sb + (h * 2 + 1) * 512 + lane * 8);
      float4_ c = {0.f, 0.f, 0.f, 0.f};
      c = __builtin_amdgcn_mfma_f32_16x16x32_bf16(aqw0, b0, c, 0, 0, 0);
      c = __builtin_amdgcn_mfma_f32_16x16x32_bf16(aqw1, b1, c, 0, 0, 0);
      ac[h] = c;
    }
#pragma unroll
    for (int tt = 0; tt < 3; ++tt) {
      float4_ d = {0.f, 0.f, 0.f, 0.f};
      d = __builtin_amdgcn_mfma_f32_16x16x32_bf16(aqr0, rb0[tt], d, 0, 0, 0);
      d = __builtin_amdgcn_mfma_f32_16x16x32_bf16(aqr1, rb1[tt], d, 0, 0, 0);
#pragma unroll
      for (int rg = 0; rg < 4; ++rg) {
        int row = quad * 4 + rg;
        Dw[row * 66 + tt * 16 + l16 + row] = d[rg];
      }
    }
    float s[2][4];
#pragma unroll
    for (int half = 0; half < 2; ++half) {
#pragma unroll
      for (int rg = 0; rg < 4; ++rg) {
        int row = quad * 4 + rg;
        int jloc = half * 16 + l16;
        float bd = Dw[row * 66 + jloc + 15];
        float sv = (ac[half][rg] + bd) * SL2E;
        s[half][rg] = (j0 + jloc > i0w + row + MLEN) ? -INFINITY : sv;
      }
    }
#pragma unroll
    for (int rg = 0; rg < 4; ++rg) {
      float mx = row_max16(fmaxf(s[0][rg], s[1][rg]));
      float mn = fmaxf(mrow[rg], mx);
      float alpha = __builtin_amdgcn_exp2f(mrow[rg] - mn);
      float p0 = __builtin_amdgcn_exp2f(s[0][rg] - mn);
      float p1 = __builtin_amdgcn_exp2f(s[1][rg] - mn);
      lpart[rg] = lpart[rg] * alpha + (p0 + p1);
      mrow[rg] = mn;
#pragma unroll
      for (int t = 0; t < 4; ++t) O[t][rg] *= alpha;
      int row = quad * 4 + rg;
      int idx0 = (l16 >> 3) * 128 + row * 8 + (l16 & 7);
      Pw[idx0] = to_bf16(p0);
      Pw[idx0 + 256] = to_bf16(p1);
    }
    short8 pfrag = *(const short8*)(Pw + lane * 8);
#pragma unroll
    for (int t = 0; t < 4; ++t) {
      short8 vfrag = *(const short8*)(sb + (4 + t) * 512 + lane * 8);
      O[t] = __builtin_amdgcn_mfma_f32_16x16x32_bf16(pfrag, vfrag, O[t], 0, 0, 0);
    }

    __builtin_amdgcn_sched_barrier(0);
    __builtin_amdgcn_s_barrier();
    __builtin_amdgcn_sched_barrier(0);
    int jn = k + 2;
    if (jn > c1 - 1) jn = c1 - 1;
    issue_dma(jn, k & 1);
  }

  // Epilogue: store unnormalized O (bf16) + per-row (m, l).
  float lsum[4];
#pragma unroll
  for (int rg = 0; rg < 4; ++rg) lsum[rg] = row_sum16(lpart[rg]);
  ushort* op = Opart + (size_t)seg * QLEN * BSZ * DM;
  float2* mlp = (float2*)ml;
#pragma unroll
  for (int rg = 0; rg < 4; ++rg) {
    int row = quad * 4 + rg;
    if (l16 == 0) {
      mlp[((size_t)seg * QLEN * BSZ + (size_t)(i0w + row) * BSZ + b) * NH + n] =
          float2{mrow[rg], lsum[rg]};
    }
#pragma unroll
    for (int t = 0; t < 4; ++t) {
      op[((size_t)(i0w + row) * BSZ + b) * DM + n * DH + t * 16 + l16] =
          to_bf16(O[t][rg]);
    }
  }
}

// ---------------------------------------------------------------------------
// Combine the two key segments: out = (O0*a0 + O1*a1) / (l0*a0 + l1*a1),
// a_i = exp2(m_i - max(m0,m1)).  One block per (i,b) row; 2 cols/thread.
// ---------------------------------------------------------------------------
__global__ __launch_bounds__(256) void attn_combine(
    const ushort* __restrict__ Opart, const float* __restrict__ ml,
    ushort* __restrict__ avbf) {
  const int row = blockIdx.x;          // i*BSZ + b
  const int tid = threadIdx.x;
  const int col = tid * 2;
  const int h = col >> 6;
  const float2* mlp = (const float2*)ml;
  float2 a = mlp[(size_t)row * NH + h];
  float2 c = mlp[((size_t)QLEN * BSZ + row) * NH + h];
  float M = fmaxf(a.x, c.x);
  float e0 = __builtin_amdgcn_exp2f(a.x - M);
  float e1 = __builtin_amdgcn_exp2f(c.x - M);
  float inv = 1.f / (a.y * e0 + c.y * e1);
  float s0 = e0 * inv, s1 = e1 * inv;
  size_t base = (size_t)row * DM + col;
  ushort2 o0 = *(const ushort2*)(Opart + base);
  ushort2 o1 = *(const ushort2*)(Opart + (size_t)QLEN * BSZ * DM + base);
  ushort2 o;
  o.x = to_bf16(bf16_to_f(o0.x) * s0 + bf16_to_f(o1.x) * s1);
  o.y = to_bf16(bf16_to_f(o0.y) * s0 + bf16_to_f(o1.y) * s1);
  *(ushort2*)(avbf + base) = o;
}

extern "C" void kernel_launch(void* const* d_in, const int* in_sizes, int n_in,
                              void* d_out, int out_size, void* d_ws, size_t ws_size,
                              hipStream_t stream) {
  const float* w    = (const float*)d_in[0];
  const float* r    = (const float*)d_in[1];
  const float* rwb  = (const float*)d_in[2];
  const float* rrb  = (const float*)d_in[3];
  const float* mems = (const float*)d_in[4];
  const float* Wq   = (const float*)d_in[5];
  const float* Wkv  = (const float*)d_in[6];
  const float* Wr   = (const float*)d_in[7];
  const float* Wo   = (const float*)d_in[8];
  const float* ln_g = (const float*)d_in[9];
  const float* ln_b = (const float*)d_in[10];
  float* out = (float*)d_out;

  char* p = (char*)d_ws;
  auto alloc = [&](size_t bytes) {
    char* q = p;
    p += (bytes + 255) & ~(size_t)255;
    return q;
  };
  ushort* WqT   = (ushort*)alloc((size_t)DM * DM * 2);
  ushort* WkvT  = (ushort*)alloc((size_t)2 * DM * DM * 2);
  ushort* WrT   = (ushort*)alloc((size_t)DM * DM * 2);
  ushort* WoT   = (ushort*)alloc((size_t)DM * DM * 2);
  ushort* qw    = (ushort*)alloc((size_t)BSZ * NH * QLEN * DH * 2);     // 4 MB
  ushort* qr    = (ushort*)alloc((size_t)BSZ * NH * QLEN * DH * 2);     // 4 MB
  ushort* k2    = (ushort*)alloc((size_t)BSZ * NH * 64 * 4 * 512 * 2);  // 8 MB
  ushort* v2    = (ushort*)alloc((size_t)BSZ * NH * 64 * 4 * 512 * 2);  // 8 MB
  ushort* rk2   = (ushort*)alloc((size_t)NH * RK_ROWS * DH * 2);        // ~2.1 MB
  ushort* avbf  = (ushort*)alloc((size_t)QLEN * BSZ * DM * 2);          // 4 MB
  ushort* Opart = (ushort*)alloc((size_t)2 * QLEN * BSZ * DM * 2);      // 8 MB
  float*  ml    = (float*)alloc((size_t)2 * QLEN * BSZ * NH * 2 * 4);   // 512 KB
  // y (8 MB f32) aliases k2: k2 fully consumed by attn before mfma_out runs.
  float* y = (float*)k2;

  wtrans_all<<<dim3(16, 32, 4), dim3(256), 0, stream>>>(
      Wq, Wkv, Wr, Wo, WqT, WkvT, WrT, WoT);
  proj_all<<<dim3(704), dim3(256), 0, stream>>>(
      w, mems, r, WqT, WkvT, WrT, rwb, rrb, qw, qr, k2, v2, rk2);
  attn_mfma<<<dim3(QLEN / 64, NH, BSZ * 2), dim3(256), 0, stream>>>(
      qw, qr, k2, v2, rk2, Opart, ml);
  attn_combine<<<dim3(QLEN * BSZ), dim3(256), 0, stream>>>(Opart, ml, avbf);
  mfma_out<<<dim3(32, 4), dim3(256), 0, stream>>>(avbf, WoT, y);
  ln_fuse<<<dim3(QLEN * BSZ / 4), dim3(256), 0, stream>>>(y, w, ln_g, ln_b, out);
}